// Round 10
// baseline (123.580 us; speedup 1.0000x reference)
//
#include <hip/hip_runtime.h>
#include <hip/hip_fp16.h>

#define NCELL 4096

typedef _Float16 f16x8 __attribute__((ext_vector_type(8)));
typedef float f32x4 __attribute__((ext_vector_type(4)));

__device__ __forceinline__ unsigned int packrn(float a, float b) {
    __half2 h = __floats2half2_rn(a, b);
    union { __half2 h; unsigned int u; } x; x.h = h; return x.u;
}

__device__ __forceinline__ int cell_of(float x0, float x1, float x2) {
    int i0 = (int)(x0 / 0.1875f + 8.0f);
    int i1 = (int)(x1 / 0.1875f + 8.0f);
    int i2 = (int)(x2 / 0.1875f + 8.0f);
    i0 = i0 < 0 ? 0 : (i0 > 15 ? 15 : i0);
    i1 = i1 < 0 ? 0 : (i1 > 15 ? 15 : i1);
    i2 = i2 < 0 ? 0 : (i2 > 15 ? 15 : i2);
    return (i0 * 16 + i1) * 16 + i2;
}

__global__ void k_count(const float* __restrict__ xs, int* __restrict__ counts,
                        float* __restrict__ out, int P) {
    int p = blockIdx.x * blockDim.x + threadIdx.x;
    if (p >= P) return;
    float x0 = xs[p * 3 + 0], x1 = xs[p * 3 + 1], x2 = xs[p * 3 + 2];
    bool m = (fabsf(x0) < 1.5f) && (fabsf(x1) < 1.5f) && (fabsf(x2) < 1.5f);
    if (m) {
        atomicAdd(&counts[cell_of(x0, x1, x2)], 1);
    } else {
        out[p * 3 + 0] = 0.0f;
        out[p * 3 + 1] = 0.0f;
        out[p * 3 + 2] = 0.0f;
        out[3 * P + p] = 0.0f;
    }
}

__global__ void k_scan(const int* __restrict__ counts, int* __restrict__ offsets,
                       int* __restrict__ cursor) {
    int l = threadIdx.x;
    int base = l * 64;
    int s = 0;
    for (int k = 0; k < 64; k++) s += counts[base + k];
    int incl = s;
    for (int d = 1; d < 64; d <<= 1) {
        int v = __shfl_up(incl, d, 64);
        if (l >= d) incl += v;
    }
    int run = incl - s;
    for (int k = 0; k < 64; k++) {
        offsets[base + k] = run;
        cursor[base + k] = run;
        run += counts[base + k];
    }
    if (l == 63) offsets[4096] = run;
}

__global__ void k_scatter(const float* __restrict__ xs, int* __restrict__ cursor,
                          int* __restrict__ sorted, int P) {
    int p = blockIdx.x * blockDim.x + threadIdx.x;
    if (p >= P) return;
    float x0 = xs[p * 3 + 0], x1 = xs[p * 3 + 1], x2 = xs[p * 3 + 2];
    bool m = (fabsf(x0) < 1.5f) && (fabsf(x1) < 1.5f) && (fabsf(x2) < 1.5f);
    if (!m) return;
    int c = cell_of(x0, x1, x2);
    int pos = atomicAdd(&cursor[c], 1);
    sorted[pos] = p;
}

// ---- MFMA helpers ----
// B-frag: frag-linear storage, lane l reads its 16B at blk*1024 + l*16 (conflict-free).
__device__ __forceinline__ f16x8 ldB(const char* wb, int off, int blk, int lane) {
    return *(const f16x8*)(wb + off + blk * 1024 + lane * 16);
}
// A-frag: act[p][k] f16, row stride 128B, XOR-swizzled (G4: 128B rows = 32-way conflict).
__device__ __forceinline__ f16x8 ldA(const char* act, int lane, int ks) {
    int p = lane & 15, g = lane >> 4;
    int byte = (p * 128 + ks * 64 + g * 16) ^ ((p & 7) << 4);
    return *(const f16x8*)(act + byte);
}
// D -> act f16 store at column kcol. D layout: col=lane&15 (caller uses), row=(lane>>4)*4+r.
__device__ __forceinline__ void stD(char* act, int kcol, f32x4 acc, bool relu, int g4) {
#pragma unroll
    for (int r = 0; r < 4; r++) {
        int p = g4 * 4 + r;
        float v = acc[r];
        if (relu) v = fmaxf(v, 0.0f);
        *(_Float16*)(act + ((p * 128 + kcol * 2) ^ ((p & 7) << 4))) = (_Float16)v;
    }
}

// Stage a weight matrix into MFMA B-fragment-linear f16 LDS.
// frag value for (blk=n*nks+ks, lane l, uint m): halves k0=ks*32+(l>>4)*8+2m, k0+1 of col 16n+(l&15).
__device__ __forceinline__ void stage_frag(char* wb, int off, const float* __restrict__ W,
                                           int ntile, int nks, int Krows, int Ncols,
                                           int stride, int lane) {
    int total = ntile * nks * 256;
    unsigned int* dst = (unsigned int*)(wb + off);
    for (int e = lane; e < total; e += 64) {
        int m = e & 3;
        int l = (e >> 2) & 63;
        int blk = e >> 8;
        int ks = blk % nks;
        int n = blk / nks;
        int c = l & 15, gg = l >> 4;
        int k0 = ks * 32 + gg * 8 + 2 * m;
        int col = 16 * n + c;
        float va = (k0 < Krows && col < Ncols) ? W[k0 * stride + col] : 0.0f;
        float vb = (k0 + 1 < Krows && col < Ncols) ? W[(k0 + 1) * stride + col] : 0.0f;
        dst[blk * 256 + l * 4 + m] = packrn(va, vb);
    }
}

#define MFMA16(a, b, c) __builtin_amdgcn_mfma_f32_16x16x32_f16((a), (b), (c), 0, 0, 0)

// wB layer offsets (bytes): W1@0 (4 blks), W2@4096 (3), W3@7168 (2), W4@9216 (4), W5@13312 (1)
__global__ void __launch_bounds__(64) k_mlp(
    const float* __restrict__ xs, const float* __restrict__ dvs,
    const float* __restrict__ w1g, const float* __restrict__ b1g,
    const float* __restrict__ w2g, const float* __restrict__ b2g,
    const float* __restrict__ w3g, const float* __restrict__ b3g,
    const float* __restrict__ w4g, const float* __restrict__ b4g,
    const float* __restrict__ w5g, const float* __restrict__ b5g,
    const int* __restrict__ offsets, const int* __restrict__ sorted,
    float* __restrict__ out, int P) {
    __shared__ __align__(16) char wB[14336];
    __shared__ __align__(16) char actA[2048];  // [16 p][64 k] f16, swizzled
    __shared__ __align__(16) char actB[2048];
    __shared__ float bias[160];  // b1@0[32] b2@32[48] b3@80[32] b4@112[32] b5@144[16]
    __shared__ float sig[16];
    __shared__ int idxL[16];

    int cell = blockIdx.x;
    int start = offsets[cell], end = offsets[cell + 1];
    if (start >= end) return;
    int lane = threadIdx.x;
    int cidx = lane & 15;
    int g4 = lane >> 4;

    // ---- stage weights (once per cell) ----
    stage_frag(wB, 0,     w1g + (size_t)cell * 2016, 2, 2, 63, 32, 32, lane);
    stage_frag(wB, 4096,  w2g + (size_t)cell * 1056, 3, 1, 32, 33, 33, lane);
    stage_frag(wB, 7168,  w3g + (size_t)cell * 1024, 2, 1, 32, 32, 32, lane);
    stage_frag(wB, 9216,  w4g + (size_t)cell * 1888, 2, 2, 59, 32, 32, lane);
    stage_frag(wB, 13312, w5g + (size_t)cell * 96,   1, 1, 32, 3, 3, lane);
    for (int e = lane; e < 160; e += 64) {
        float v = 0.0f;
        if (e < 32) v = b1g[(size_t)cell * 32 + e];
        else if (e < 80) { int q = e - 32; if (q < 33) v = b2g[(size_t)cell * 33 + q]; }
        else if (e < 112) v = b3g[(size_t)cell * 32 + (e - 80)];
        else if (e < 144) v = b4g[(size_t)cell * 32 + (e - 112)];
        else { int q = e - 144; if (q < 3) v = b5g[(size_t)cell * 3 + q]; }
        bias[e] = v;
    }
    __syncthreads();  // single wave; harmless, orders staging vs loop

    for (int t0 = start; t0 < end; t0 += 16) {
        int nv = end - t0; if (nv > 16) nv = 16;

        // ---- load this tile's 16 points (all 4 groups load same 16; L1 absorbs) ----
        int t = t0 + cidx;
        int idx = sorted[(cidx < nv) ? t : start];
        if (g4 == 0) idxL[cidx] = idx;
        float x0 = xs[idx * 3 + 0], x1 = xs[idx * 3 + 1], x2 = xs[idx * 3 + 2];
        float d0 = dvs[idx * 3 + 0], d1 = dvs[idx * 3 + 1], d2 = dvs[idx * 3 + 2];

        // ---- positional encoding -> actA[p][0..63] (lane covers point cidx, k 16*g4..+15)
        {
            float ev[16];
#pragma unroll
            for (int i = 0; i < 16; i++) {
                int k = g4 * 16 + i;
                float v;
                if (k < 3) v = (k == 0) ? x0 : ((k == 1) ? x1 : x2);
                else if (k < 63) {
                    int q = k - 3, j = q / 6, r = q % 6, a = r % 3;
                    float xx = (a == 0) ? x0 : ((a == 1) ? x1 : x2);
                    float arg = (float)(1 << j) * xx;
                    v = (r < 3) ? __sinf(arg) : __cosf(arg);
                } else v = 0.0f;
                ev[i] = v;
            }
            uint4 u0, u1;
            u0.x = packrn(ev[0], ev[1]);  u0.y = packrn(ev[2], ev[3]);
            u0.z = packrn(ev[4], ev[5]);  u0.w = packrn(ev[6], ev[7]);
            u1.x = packrn(ev[8], ev[9]);  u1.y = packrn(ev[10], ev[11]);
            u1.z = packrn(ev[12], ev[13]); u1.w = packrn(ev[14], ev[15]);
            int sw = (cidx & 7) << 4;
            *(uint4*)(actA + ((cidx * 128 + g4 * 32) ^ sw)) = u0;
            *(uint4*)(actA + ((cidx * 128 + g4 * 32 + 16) ^ sw)) = u1;
        }
        // ---- direction encoding -> actB[p][32..63] (k' = 8*g4..+7; 27 real + pad)
        {
            float ev[8];
#pragma unroll
            for (int i = 0; i < 8; i++) {
                int k = g4 * 8 + i;
                float v;
                if (k < 3) v = (k == 0) ? d0 : ((k == 1) ? d1 : d2);
                else if (k < 27) {
                    int q = k - 3, j = q / 6, r = q % 6, a = r % 3;
                    float xx = (a == 0) ? d0 : ((a == 1) ? d1 : d2);
                    float arg = (float)(1 << j) * xx;
                    v = (r < 3) ? __sinf(arg) : __cosf(arg);
                } else v = 0.0f;
                ev[i] = v;
            }
            uint4 u;
            u.x = packrn(ev[0], ev[1]); u.y = packrn(ev[2], ev[3]);
            u.z = packrn(ev[4], ev[5]); u.w = packrn(ev[6], ev[7]);
            *(uint4*)(actB + ((cidx * 128 + 64 + g4 * 16) ^ ((cidx & 7) << 4))) = u;
        }

        // ---- L1: enc(64) -> 32, relu.  out -> actB[0..31]
        {
            f16x8 a0 = ldA(actA, lane, 0);
            f16x8 a1 = ldA(actA, lane, 1);
#pragma unroll
            for (int n = 0; n < 2; n++) {
                float bv = bias[0 + 16 * n + cidx];
                f32x4 acc = {bv, bv, bv, bv};
                acc = MFMA16(a0, ldB(wB, 0, n * 2 + 0, lane), acc);
                acc = MFMA16(a1, ldB(wB, 0, n * 2 + 1, lane), acc);
                stD(actB, 16 * n + cidx, acc, true, g4);
            }
        }
        // ---- L2: 32 -> 33, relu. col0 -> sigma; cols1..32 -> actA[0..31]
        {
            f16x8 a2 = ldA(actB, lane, 0);
#pragma unroll
            for (int n = 0; n < 3; n++) {
                float bv = bias[32 + 16 * n + cidx];
                f32x4 acc = {bv, bv, bv, bv};
                acc = MFMA16(a2, ldB(wB, 4096, n, lane), acc);
                int C = 16 * n + cidx;
                if (C == 0) {
#pragma unroll
                    for (int r = 0; r < 4; r++) sig[g4 * 4 + r] = fmaxf(acc[r], 0.0f);
                } else if (C <= 32) {
                    stD(actA, C - 1, acc, true, g4);
                }
            }
        }
        // ---- L3: 32 -> 32, no act. out -> actB[0..31]
        {
            f16x8 a3 = ldA(actA, lane, 0);
#pragma unroll
            for (int n = 0; n < 2; n++) {
                float bv = bias[80 + 16 * n + cidx];
                f32x4 acc = {bv, bv, bv, bv};
                acc = MFMA16(a3, ldB(wB, 7168, n, lane), acc);
                stD(actB, 16 * n + cidx, acc, false, g4);
            }
        }
        // ---- L4: [h3|ed](64) -> 32, relu. out -> actA[0..31]
        {
            f16x8 a4a = ldA(actB, lane, 0);
            f16x8 a4b = ldA(actB, lane, 1);
#pragma unroll
            for (int n = 0; n < 2; n++) {
                float bv = bias[112 + 16 * n + cidx];
                f32x4 acc = {bv, bv, bv, bv};
                acc = MFMA16(a4a, ldB(wB, 9216, n * 2 + 0, lane), acc);
                acc = MFMA16(a4b, ldB(wB, 9216, n * 2 + 1, lane), acc);
                stD(actA, 16 * n + cidx, acc, true, g4);
            }
        }
        // ---- L5: 32 -> 3, sigmoid; + sigma out
        {
            f16x8 a5 = ldA(actA, lane, 0);
            float bv = bias[144 + cidx];
            f32x4 acc = {bv, bv, bv, bv};
            acc = MFMA16(a5, ldB(wB, 13312, 0, lane), acc);
            if (cidx < 3) {
#pragma unroll
                for (int r = 0; r < 4; r++) {
                    int p = g4 * 4 + r;
                    if (p < nv) out[(size_t)idxL[p] * 3 + cidx] = 1.0f / (1.0f + __expf(-acc[r]));
                }
            } else if (cidx == 3) {
#pragma unroll
                for (int r = 0; r < 4; r++) {
                    int p = g4 * 4 + r;
                    if (p < nv) out[(size_t)3 * P + idxL[p]] = sig[p];
                }
            }
        }
    }
}

extern "C" void kernel_launch(void* const* d_in, const int* in_sizes, int n_in,
                              void* d_out, int out_size, void* d_ws, size_t ws_size,
                              hipStream_t stream) {
    const float* xs = (const float*)d_in[0];
    const float* dv = (const float*)d_in[1];
    const float* w1 = (const float*)d_in[2];
    const float* b1 = (const float*)d_in[3];
    const float* w2 = (const float*)d_in[4];
    const float* b2 = (const float*)d_in[5];
    const float* w3 = (const float*)d_in[6];
    const float* b3 = (const float*)d_in[7];
    const float* w4 = (const float*)d_in[8];
    const float* b4 = (const float*)d_in[9];
    const float* w5 = (const float*)d_in[10];
    const float* b5 = (const float*)d_in[11];
    float* out = (float*)d_out;
    int P = in_sizes[0] / 3;

    int* counts = (int*)d_ws;
    int* offsets = counts + 4096;
    int* cursor = offsets + 4104;
    int* sorted = cursor + 4096;

    hipMemsetAsync(counts, 0, 4096 * sizeof(int), stream);

    int blk = 256;
    int grd = (P + blk - 1) / blk;
    k_count<<<grd, blk, 0, stream>>>(xs, counts, out, P);
    k_scan<<<1, 64, 0, stream>>>(counts, offsets, cursor);
    k_scatter<<<grd, blk, 0, stream>>>(xs, cursor, sorted, P);
    k_mlp<<<NCELL, 64, 0, stream>>>(xs, dv, w1, b1, w2, b2, w3, b3, w4, b4, w5, b5,
                                    offsets, sorted, out, P);
}

// Round 11
// 77.401 us; speedup vs baseline: 1.5966x; 1.5966x over previous
//
#include <hip/hip_runtime.h>
#include <hip/hip_fp16.h>

#define NCELL 4096

typedef _Float16 f16x8 __attribute__((ext_vector_type(8)));
typedef float f32x4 __attribute__((ext_vector_type(4)));

__device__ __forceinline__ unsigned int packrn(float a, float b) {
    __half2 h = __floats2half2_rn(a, b);
    union { __half2 h; unsigned int u; } x; x.h = h; return x.u;
}

__device__ __forceinline__ int cell_of(float x0, float x1, float x2) {
    int i0 = (int)(x0 / 0.1875f + 8.0f);
    int i1 = (int)(x1 / 0.1875f + 8.0f);
    int i2 = (int)(x2 / 0.1875f + 8.0f);
    i0 = i0 < 0 ? 0 : (i0 > 15 ? 15 : i0);
    i1 = i1 < 0 ? 0 : (i1 > 15 ? 15 : i1);
    i2 = i2 < 0 ? 0 : (i2 > 15 ? 15 : i2);
    return (i0 * 16 + i1) * 16 + i2;
}

__global__ void k_count(const float* __restrict__ xs, int* __restrict__ counts,
                        float* __restrict__ out, int P) {
    int p = blockIdx.x * blockDim.x + threadIdx.x;
    if (p >= P) return;
    float x0 = xs[p * 3 + 0], x1 = xs[p * 3 + 1], x2 = xs[p * 3 + 2];
    bool m = (fabsf(x0) < 1.5f) && (fabsf(x1) < 1.5f) && (fabsf(x2) < 1.5f);
    if (m) {
        atomicAdd(&counts[cell_of(x0, x1, x2)], 1);
    } else {
        out[p * 3 + 0] = 0.0f;
        out[p * 3 + 1] = 0.0f;
        out[p * 3 + 2] = 0.0f;
        out[3 * P + p] = 0.0f;
    }
}

__global__ void k_scan(const int* __restrict__ counts, int* __restrict__ offsets,
                       int* __restrict__ cursor) {
    int l = threadIdx.x;
    int base = l * 64;
    int s = 0;
    for (int k = 0; k < 64; k++) s += counts[base + k];
    int incl = s;
    for (int d = 1; d < 64; d <<= 1) {
        int v = __shfl_up(incl, d, 64);
        if (l >= d) incl += v;
    }
    int run = incl - s;
    for (int k = 0; k < 64; k++) {
        offsets[base + k] = run;
        cursor[base + k] = run;
        run += counts[base + k];
    }
    if (l == 63) offsets[4096] = run;
}

__global__ void k_scatter(const float* __restrict__ xs, int* __restrict__ cursor,
                          int* __restrict__ sorted, int P) {
    int p = blockIdx.x * blockDim.x + threadIdx.x;
    if (p >= P) return;
    float x0 = xs[p * 3 + 0], x1 = xs[p * 3 + 1], x2 = xs[p * 3 + 2];
    bool m = (fabsf(x0) < 1.5f) && (fabsf(x1) < 1.5f) && (fabsf(x2) < 1.5f);
    if (!m) return;
    int c = cell_of(x0, x1, x2);
    int pos = atomicAdd(&cursor[c], 1);
    sorted[pos] = p;
}

// ---- MFMA helpers (identical to validated R10) ----
__device__ __forceinline__ f16x8 ldB(const char* wb, int off, int blk, int lane) {
    return *(const f16x8*)(wb + off + blk * 1024 + lane * 16);
}
__device__ __forceinline__ f16x8 ldA(const char* act, int lane, int ks) {
    int p = lane & 15, g = lane >> 4;
    int byte = (p * 128 + ks * 64 + g * 16) ^ ((p & 7) << 4);
    return *(const f16x8*)(act + byte);
}
__device__ __forceinline__ void stD(char* act, int kcol, f32x4 acc, bool relu, int g4) {
#pragma unroll
    for (int r = 0; r < 4; r++) {
        int p = g4 * 4 + r;
        float v = acc[r];
        if (relu) v = fmaxf(v, 0.0f);
        *(_Float16*)(act + ((p * 128 + kcol * 2) ^ ((p & 7) << 4))) = (_Float16)v;
    }
}

// Batched staging: phase 1 issues ALL of this lane's independent global loads
// into compile-time-indexed register arrays (one vmcnt drain per matrix, not
// per element); phase 2 packs + writes to the SAME frag-linear layout R10
// validated. OOB pad slots use clamped in-bounds addresses (small finite
// garbage; k-pads hit zero A-fragments, col-pads feed never-stored D cols).
template <int ITERS, int NKS>
__device__ __forceinline__ void stage_fragC(char* wb, int off,
                                            const float* __restrict__ W,
                                            int Krows, int Ncols, int stride,
                                            int lane) {
    float va[ITERS], vb[ITERS];
    unsigned int* dst = (unsigned int*)(wb + off);
#pragma unroll
    for (int j = 0; j < ITERS; j++) {
        int e = lane + 64 * j;
        int m = e & 3;
        int l = (e >> 2) & 63;
        int blk = e >> 8;
        int ks = blk % NKS;
        int n = blk / NKS;
        int c = l & 15, gg = l >> 4;
        int k0 = ks * 32 + gg * 8 + 2 * m;
        int col = 16 * n + c;
        int ka = (k0 < Krows) ? k0 : (Krows - 1);
        int kb = (k0 + 1 < Krows) ? (k0 + 1) : (Krows - 1);
        int cc = (col < Ncols) ? col : (Ncols - 1);
        va[j] = W[ka * stride + cc];
        vb[j] = W[kb * stride + cc];
    }
#pragma unroll
    for (int j = 0; j < ITERS; j++) {
        int e = lane + 64 * j;
        int m = e & 3;
        int l = (e >> 2) & 63;
        int blk = e >> 8;
        // zero the k-pad/col-pad slots' effect is guaranteed by A-side zeros /
        // unused D cols; values here are small finite weights (no inf/NaN).
        dst[blk * 256 + l * 4 + m] = packrn(va[j], vb[j]);
    }
}

#define MFMA16(a, b, c) __builtin_amdgcn_mfma_f32_16x16x32_f16((a), (b), (c), 0, 0, 0)

// wB offsets (bytes): W1@0 (4 blks), W2@4096 (3), W3@7168 (2), W4@9216 (4), W5@13312 (1)
__global__ void __launch_bounds__(64) k_mlp(
    const float* __restrict__ xs, const float* __restrict__ dvs,
    const float* __restrict__ w1g, const float* __restrict__ b1g,
    const float* __restrict__ w2g, const float* __restrict__ b2g,
    const float* __restrict__ w3g, const float* __restrict__ b3g,
    const float* __restrict__ w4g, const float* __restrict__ b4g,
    const float* __restrict__ w5g, const float* __restrict__ b5g,
    const int* __restrict__ offsets, const int* __restrict__ sorted,
    float* __restrict__ out, int P) {
    __shared__ __align__(16) char wB[14336];
    __shared__ __align__(16) char actA[2048];
    __shared__ __align__(16) char actB[2048];
    __shared__ float bias[160];
    __shared__ float sig[16];
    __shared__ int idxL[16];

    int cell = blockIdx.x;
    int start = offsets[cell], end = offsets[cell + 1];
    if (start >= end) return;
    int lane = threadIdx.x;
    int cidx = lane & 15;
    int g4 = lane >> 4;

    // ---- stage weights (batched) ----
    stage_fragC<16, 2>(wB, 0,     w1g + (size_t)cell * 2016, 63, 32, 32, lane);
    stage_fragC<12, 1>(wB, 4096,  w2g + (size_t)cell * 1056, 32, 33, 33, lane);
    stage_fragC<8, 1>(wB, 7168,   w3g + (size_t)cell * 1024, 32, 32, 32, lane);
    stage_fragC<16, 2>(wB, 9216,  w4g + (size_t)cell * 1888, 59, 32, 32, lane);
    stage_fragC<4, 1>(wB, 13312,  w5g + (size_t)cell * 96,   32, 3, 3, lane);
    {
        float bv[3];
#pragma unroll
        for (int j = 0; j < 3; j++) {
            int e = lane + 64 * j;
            float v = 0.0f;
            if (e < 32) v = b1g[(size_t)cell * 32 + e];
            else if (e < 80) { int q = e - 32; v = b2g[(size_t)cell * 33 + ((q < 33) ? q : 0)]; if (q >= 33) v = 0.0f; }
            else if (e < 112) v = b3g[(size_t)cell * 32 + (e - 80)];
            else if (e < 144) v = b4g[(size_t)cell * 32 + (e - 112)];
            else if (e < 160) { int q = e - 144; v = (q < 3) ? b5g[(size_t)cell * 3 + q] : 0.0f; }
            bv[j] = v;
        }
#pragma unroll
        for (int j = 0; j < 3; j++) {
            int e = lane + 64 * j;
            if (e < 160) bias[e] = bv[j];
        }
    }
    __syncthreads();

    for (int t0 = start; t0 < end; t0 += 16) {
        int nv = end - t0; if (nv > 16) nv = 16;

        int t = t0 + cidx;
        int idx = sorted[(cidx < nv) ? t : start];
        if (g4 == 0) idxL[cidx] = idx;
        float x0 = xs[idx * 3 + 0], x1 = xs[idx * 3 + 1], x2 = xs[idx * 3 + 2];
        float d0 = dvs[idx * 3 + 0], d1 = dvs[idx * 3 + 1], d2 = dvs[idx * 3 + 2];

        // ---- positional encoding -> actA[p][0..63]
        {
            float ev[16];
#pragma unroll
            for (int i = 0; i < 16; i++) {
                int k = g4 * 16 + i;
                float v;
                if (k < 3) v = (k == 0) ? x0 : ((k == 1) ? x1 : x2);
                else if (k < 63) {
                    int q = k - 3, j = q / 6, r = q % 6, a = r % 3;
                    float xx = (a == 0) ? x0 : ((a == 1) ? x1 : x2);
                    float arg = (float)(1 << j) * xx;
                    v = (r < 3) ? __sinf(arg) : __cosf(arg);
                } else v = 0.0f;
                ev[i] = v;
            }
            uint4 u0, u1;
            u0.x = packrn(ev[0], ev[1]);  u0.y = packrn(ev[2], ev[3]);
            u0.z = packrn(ev[4], ev[5]);  u0.w = packrn(ev[6], ev[7]);
            u1.x = packrn(ev[8], ev[9]);  u1.y = packrn(ev[10], ev[11]);
            u1.z = packrn(ev[12], ev[13]); u1.w = packrn(ev[14], ev[15]);
            int sw = (cidx & 7) << 4;
            *(uint4*)(actA + ((cidx * 128 + g4 * 32) ^ sw)) = u0;
            *(uint4*)(actA + ((cidx * 128 + g4 * 32 + 16) ^ sw)) = u1;
        }
        // ---- direction encoding -> actB[p][32..63]
        {
            float ev[8];
#pragma unroll
            for (int i = 0; i < 8; i++) {
                int k = g4 * 8 + i;
                float v;
                if (k < 3) v = (k == 0) ? d0 : ((k == 1) ? d1 : d2);
                else if (k < 27) {
                    int q = k - 3, j = q / 6, r = q % 6, a = r % 3;
                    float xx = (a == 0) ? d0 : ((a == 1) ? d1 : d2);
                    float arg = (float)(1 << j) * xx;
                    v = (r < 3) ? __sinf(arg) : __cosf(arg);
                } else v = 0.0f;
                ev[i] = v;
            }
            uint4 u;
            u.x = packrn(ev[0], ev[1]); u.y = packrn(ev[2], ev[3]);
            u.z = packrn(ev[4], ev[5]); u.w = packrn(ev[6], ev[7]);
            *(uint4*)(actB + ((cidx * 128 + 64 + g4 * 16) ^ ((cidx & 7) << 4))) = u;
        }

        // ---- L1: enc(64) -> 32, relu -> actB[0..31]
        {
            f16x8 a0 = ldA(actA, lane, 0);
            f16x8 a1 = ldA(actA, lane, 1);
#pragma unroll
            for (int n = 0; n < 2; n++) {
                float bv = bias[0 + 16 * n + cidx];
                f32x4 acc = {bv, bv, bv, bv};
                acc = MFMA16(a0, ldB(wB, 0, n * 2 + 0, lane), acc);
                acc = MFMA16(a1, ldB(wB, 0, n * 2 + 1, lane), acc);
                stD(actB, 16 * n + cidx, acc, true, g4);
            }
        }
        // ---- L2: 32 -> 33, relu. col0 -> sigma; cols1..32 -> actA[0..31]
        {
            f16x8 a2 = ldA(actB, lane, 0);
#pragma unroll
            for (int n = 0; n < 3; n++) {
                float bv = bias[32 + 16 * n + cidx];
                f32x4 acc = {bv, bv, bv, bv};
                acc = MFMA16(a2, ldB(wB, 4096, n, lane), acc);
                int C = 16 * n + cidx;
                if (C == 0) {
#pragma unroll
                    for (int r = 0; r < 4; r++) sig[g4 * 4 + r] = fmaxf(acc[r], 0.0f);
                } else if (C <= 32) {
                    stD(actA, C - 1, acc, true, g4);
                }
            }
        }
        // ---- L3: 32 -> 32, no act -> actB[0..31]
        {
            f16x8 a3 = ldA(actA, lane, 0);
#pragma unroll
            for (int n = 0; n < 2; n++) {
                float bv = bias[80 + 16 * n + cidx];
                f32x4 acc = {bv, bv, bv, bv};
                acc = MFMA16(a3, ldB(wB, 7168, n, lane), acc);
                stD(actB, 16 * n + cidx, acc, false, g4);
            }
        }
        // ---- L4: [h3|ed](64) -> 32, relu -> actA[0..31]
        {
            f16x8 a4a = ldA(actB, lane, 0);
            f16x8 a4b = ldA(actB, lane, 1);
#pragma unroll
            for (int n = 0; n < 2; n++) {
                float bv = bias[112 + 16 * n + cidx];
                f32x4 acc = {bv, bv, bv, bv};
                acc = MFMA16(a4a, ldB(wB, 9216, n * 2 + 0, lane), acc);
                acc = MFMA16(a4b, ldB(wB, 9216, n * 2 + 1, lane), acc);
                stD(actA, 16 * n + cidx, acc, true, g4);
            }
        }
        // ---- L5: 32 -> 3, sigmoid; + sigma out
        {
            f16x8 a5 = ldA(actA, lane, 0);
            float bv = bias[144 + cidx];
            f32x4 acc = {bv, bv, bv, bv};
            acc = MFMA16(a5, ldB(wB, 13312, 0, lane), acc);
            if (cidx < 3) {
#pragma unroll
                for (int r = 0; r < 4; r++) {
                    int p = g4 * 4 + r;
                    if (p < nv) out[(size_t)idxL[p] * 3 + cidx] = 1.0f / (1.0f + __expf(-acc[r]));
                }
            } else if (cidx == 3) {
#pragma unroll
                for (int r = 0; r < 4; r++) {
                    int p = g4 * 4 + r;
                    if (p < nv) out[(size_t)3 * P + idxL[p]] = sig[p];
                }
            }
        }
    }
}

extern "C" void kernel_launch(void* const* d_in, const int* in_sizes, int n_in,
                              void* d_out, int out_size, void* d_ws, size_t ws_size,
                              hipStream_t stream) {
    const float* xs = (const float*)d_in[0];
    const float* dv = (const float*)d_in[1];
    const float* w1 = (const float*)d_in[2];
    const float* b1 = (const float*)d_in[3];
    const float* w2 = (const float*)d_in[4];
    const float* b2 = (const float*)d_in[5];
    const float* w3 = (const float*)d_in[6];
    const float* b3 = (const float*)d_in[7];
    const float* w4 = (const float*)d_in[8];
    const float* b4 = (const float*)d_in[9];
    const float* w5 = (const float*)d_in[10];
    const float* b5 = (const float*)d_in[11];
    float* out = (float*)d_out;
    int P = in_sizes[0] / 3;

    int* counts = (int*)d_ws;
    int* offsets = counts + 4096;
    int* cursor = offsets + 4104;
    int* sorted = cursor + 4096;

    hipMemsetAsync(counts, 0, 4096 * sizeof(int), stream);

    int blk = 256;
    int grd = (P + blk - 1) / blk;
    k_count<<<grd, blk, 0, stream>>>(xs, counts, out, P);
    k_scan<<<1, 64, 0, stream>>>(counts, offsets, cursor);
    k_scatter<<<grd, blk, 0, stream>>>(xs, cursor, sorted, P);
    k_mlp<<<NCELL, 64, 0, stream>>>(xs, dv, w1, b1, w2, b2, w3, b3, w4, b4, w5, b5,
                                    offsets, sorted, out, P);
}

// Round 12
// 72.576 us; speedup vs baseline: 1.7028x; 1.0665x over previous
//
#include <hip/hip_runtime.h>
#include <hip/hip_fp16.h>

#define NCELL 4096

typedef _Float16 f16x8 __attribute__((ext_vector_type(8)));
typedef float f32x4 __attribute__((ext_vector_type(4)));

__device__ __forceinline__ unsigned int packrn(float a, float b) {
    __half2 h = __floats2half2_rn(a, b);
    union { __half2 h; unsigned int u; } x; x.h = h; return x.u;
}

__device__ __forceinline__ int cell_of(float x0, float x1, float x2) {
    int i0 = (int)(x0 / 0.1875f + 8.0f);
    int i1 = (int)(x1 / 0.1875f + 8.0f);
    int i2 = (int)(x2 / 0.1875f + 8.0f);
    i0 = i0 < 0 ? 0 : (i0 > 15 ? 15 : i0);
    i1 = i1 < 0 ? 0 : (i1 > 15 ? 15 : i1);
    i2 = i2 < 0 ? 0 : (i2 > 15 ? 15 : i2);
    return (i0 * 16 + i1) * 16 + i2;
}

__global__ void k_count(const float* __restrict__ xs, int* __restrict__ counts,
                        float* __restrict__ out, int P) {
    int p = blockIdx.x * blockDim.x + threadIdx.x;
    if (p >= P) return;
    float x0 = xs[p * 3 + 0], x1 = xs[p * 3 + 1], x2 = xs[p * 3 + 2];
    bool m = (fabsf(x0) < 1.5f) && (fabsf(x1) < 1.5f) && (fabsf(x2) < 1.5f);
    if (m) {
        atomicAdd(&counts[cell_of(x0, x1, x2)], 1);
    } else {
        out[p * 3 + 0] = 0.0f;
        out[p * 3 + 1] = 0.0f;
        out[p * 3 + 2] = 0.0f;
        out[3 * P + p] = 0.0f;
    }
}

__global__ void k_scan(const int* __restrict__ counts, int* __restrict__ offsets,
                       int* __restrict__ cursor) {
    int l = threadIdx.x;
    int base = l * 64;
    int s = 0;
    for (int k = 0; k < 64; k++) s += counts[base + k];
    int incl = s;
    for (int d = 1; d < 64; d <<= 1) {
        int v = __shfl_up(incl, d, 64);
        if (l >= d) incl += v;
    }
    int run = incl - s;
    for (int k = 0; k < 64; k++) {
        offsets[base + k] = run;
        cursor[base + k] = run;
        run += counts[base + k];
    }
    if (l == 63) offsets[4096] = run;
}

__global__ void k_scatter(const float* __restrict__ xs, int* __restrict__ cursor,
                          int* __restrict__ sorted, int P) {
    int p = blockIdx.x * blockDim.x + threadIdx.x;
    if (p >= P) return;
    float x0 = xs[p * 3 + 0], x1 = xs[p * 3 + 1], x2 = xs[p * 3 + 2];
    bool m = (fabsf(x0) < 1.5f) && (fabsf(x1) < 1.5f) && (fabsf(x2) < 1.5f);
    if (!m) return;
    int c = cell_of(x0, x1, x2);
    int pos = atomicAdd(&cursor[c], 1);
    sorted[pos] = p;
}

// ---- MFMA helpers (identical to validated R10/R11) ----
__device__ __forceinline__ f16x8 ldB(const char* wb, int off, int blk, int lane) {
    return *(const f16x8*)(wb + off + blk * 1024 + lane * 16);
}
__device__ __forceinline__ f16x8 ldA(const char* act, int lane, int ks) {
    int p = lane & 15, g = lane >> 4;
    int byte = (p * 128 + ks * 64 + g * 16) ^ ((p & 7) << 4);
    return *(const f16x8*)(act + byte);
}
__device__ __forceinline__ void stD(char* act, int kcol, f32x4 acc, bool relu, int g4) {
#pragma unroll
    for (int r = 0; r < 4; r++) {
        int p = g4 * 4 + r;
        float v = acc[r];
        if (relu) v = fmaxf(v, 0.0f);
        *(_Float16*)(act + ((p * 128 + kcol * 2) ^ ((p & 7) << 4))) = (_Float16)v;
    }
}

// Batched staging across 256 threads: phase 1 issues all independent global
// loads into compile-time-indexed register arrays; phase 2 packs + ds_writes.
// Same frag-linear layout validated in R10; pad slots use clamped addresses.
template <int ITERS, int NKS>
__device__ __forceinline__ void stage_fragC(char* wb, int off,
                                            const float* __restrict__ W,
                                            int Krows, int Ncols, int stride,
                                            int tid) {
    float va[ITERS], vb[ITERS];
    unsigned int* dst = (unsigned int*)(wb + off);
#pragma unroll
    for (int j = 0; j < ITERS; j++) {
        int e = tid + 256 * j;
        int m = e & 3;
        int l = (e >> 2) & 63;
        int blk = e >> 8;
        int ks = blk % NKS;
        int n = blk / NKS;
        int c = l & 15, gg = l >> 4;
        int k0 = ks * 32 + gg * 8 + 2 * m;
        int col = 16 * n + c;
        int ka = (k0 < Krows) ? k0 : (Krows - 1);
        int kb = (k0 + 1 < Krows) ? (k0 + 1) : (Krows - 1);
        int cc = (col < Ncols) ? col : (Ncols - 1);
        va[j] = W[ka * stride + cc];
        vb[j] = W[kb * stride + cc];
    }
#pragma unroll
    for (int j = 0; j < ITERS; j++) {
        int e = tid + 256 * j;
        int m = e & 3;
        int l = (e >> 2) & 63;
        int blk = e >> 8;
        dst[blk * 256 + l * 4 + m] = packrn(va[j], vb[j]);
    }
}

#define MFMA16(a, b, c) __builtin_amdgcn_mfma_f32_16x16x32_f16((a), (b), (c), 0, 0, 0)

// 4 waves per block, one cell per block. Waves share one staged weight copy;
// each wave runs an independent 16-point tile pipeline (private act buffers,
// no barriers in the tile loop).
// wB offsets (bytes): W1@0 (4 blks), W2@4096 (3), W3@7168 (2), W4@9216 (4), W5@13312 (1)
__global__ void __launch_bounds__(256) k_mlp(
    const float* __restrict__ xs, const float* __restrict__ dvs,
    const float* __restrict__ w1g, const float* __restrict__ b1g,
    const float* __restrict__ w2g, const float* __restrict__ b2g,
    const float* __restrict__ w3g, const float* __restrict__ b3g,
    const float* __restrict__ w4g, const float* __restrict__ b4g,
    const float* __restrict__ w5g, const float* __restrict__ b5g,
    const int* __restrict__ offsets, const int* __restrict__ sorted,
    float* __restrict__ out, int P) {
    __shared__ __align__(16) char wB[14336];
    __shared__ __align__(16) char actAall[8192];
    __shared__ __align__(16) char actBall[8192];
    __shared__ float bias[160];
    __shared__ float sig[64];
    __shared__ int idxL[64];

    int cell = blockIdx.x;
    int start = offsets[cell], end = offsets[cell + 1];
    if (start >= end) return;
    int tid = threadIdx.x;
    int lane = tid & 63;
    int wid = tid >> 6;
    int cidx = lane & 15;
    int g4 = lane >> 4;

    // ---- stage weights (batched, split across 4 waves) ----
    stage_fragC<4, 2>(wB, 0,     w1g + (size_t)cell * 2016, 63, 32, 32, tid);
    stage_fragC<3, 1>(wB, 4096,  w2g + (size_t)cell * 1056, 32, 33, 33, tid);
    stage_fragC<2, 1>(wB, 7168,  w3g + (size_t)cell * 1024, 32, 32, 32, tid);
    stage_fragC<4, 2>(wB, 9216,  w4g + (size_t)cell * 1888, 59, 32, 32, tid);
    stage_fragC<1, 1>(wB, 13312, w5g + (size_t)cell * 96,   32, 3, 3, tid);
    if (tid < 160) {
        int e = tid;
        float v = 0.0f;
        if (e < 32) v = b1g[(size_t)cell * 32 + e];
        else if (e < 80) { int q = e - 32; v = (q < 33) ? b2g[(size_t)cell * 33 + q] : 0.0f; }
        else if (e < 112) v = b3g[(size_t)cell * 32 + (e - 80)];
        else if (e < 144) v = b4g[(size_t)cell * 32 + (e - 112)];
        else { int q = e - 144; v = (q < 3) ? b5g[(size_t)cell * 3 + q] : 0.0f; }
        bias[e] = v;
    }
    __syncthreads();

    char* actA = actAall + (wid << 11);
    char* actB = actBall + (wid << 11);
    float* sigw = sig + (wid << 4);
    int* idxw = idxL + (wid << 4);

    for (int t0 = start + (wid << 4); t0 < end; t0 += 64) {
        int nv = end - t0; if (nv > 16) nv = 16;

        int t = t0 + cidx;
        int idx = sorted[(cidx < nv) ? t : start];
        if (g4 == 0) idxw[cidx] = idx;
        float x0 = xs[idx * 3 + 0], x1 = xs[idx * 3 + 1], x2 = xs[idx * 3 + 2];
        float d0 = dvs[idx * 3 + 0], d1 = dvs[idx * 3 + 1], d2 = dvs[idx * 3 + 2];

        // ---- positional encoding -> actA[p][0..63]
        {
            float ev[16];
#pragma unroll
            for (int i = 0; i < 16; i++) {
                int k = g4 * 16 + i;
                float v;
                if (k < 3) v = (k == 0) ? x0 : ((k == 1) ? x1 : x2);
                else if (k < 63) {
                    int q = k - 3, j = q / 6, r = q % 6, a = r % 3;
                    float xx = (a == 0) ? x0 : ((a == 1) ? x1 : x2);
                    float arg = (float)(1 << j) * xx;
                    v = (r < 3) ? __sinf(arg) : __cosf(arg);
                } else v = 0.0f;
                ev[i] = v;
            }
            uint4 u0, u1;
            u0.x = packrn(ev[0], ev[1]);  u0.y = packrn(ev[2], ev[3]);
            u0.z = packrn(ev[4], ev[5]);  u0.w = packrn(ev[6], ev[7]);
            u1.x = packrn(ev[8], ev[9]);  u1.y = packrn(ev[10], ev[11]);
            u1.z = packrn(ev[12], ev[13]); u1.w = packrn(ev[14], ev[15]);
            int sw = (cidx & 7) << 4;
            *(uint4*)(actA + ((cidx * 128 + g4 * 32) ^ sw)) = u0;
            *(uint4*)(actA + ((cidx * 128 + g4 * 32 + 16) ^ sw)) = u1;
        }
        // ---- direction encoding -> actB[p][32..63]
        {
            float ev[8];
#pragma unroll
            for (int i = 0; i < 8; i++) {
                int k = g4 * 8 + i;
                float v;
                if (k < 3) v = (k == 0) ? d0 : ((k == 1) ? d1 : d2);
                else if (k < 27) {
                    int q = k - 3, j = q / 6, r = q % 6, a = r % 3;
                    float xx = (a == 0) ? d0 : ((a == 1) ? d1 : d2);
                    float arg = (float)(1 << j) * xx;
                    v = (r < 3) ? __sinf(arg) : __cosf(arg);
                } else v = 0.0f;
                ev[i] = v;
            }
            uint4 u;
            u.x = packrn(ev[0], ev[1]); u.y = packrn(ev[2], ev[3]);
            u.z = packrn(ev[4], ev[5]); u.w = packrn(ev[6], ev[7]);
            *(uint4*)(actB + ((cidx * 128 + 64 + g4 * 16) ^ ((cidx & 7) << 4))) = u;
        }

        // ---- L1: enc(64) -> 32, relu -> actB[0..31]
        {
            f16x8 a0 = ldA(actA, lane, 0);
            f16x8 a1 = ldA(actA, lane, 1);
#pragma unroll
            for (int n = 0; n < 2; n++) {
                float bv = bias[0 + 16 * n + cidx];
                f32x4 acc = {bv, bv, bv, bv};
                acc = MFMA16(a0, ldB(wB, 0, n * 2 + 0, lane), acc);
                acc = MFMA16(a1, ldB(wB, 0, n * 2 + 1, lane), acc);
                stD(actB, 16 * n + cidx, acc, true, g4);
            }
        }
        // ---- L2: 32 -> 33, relu. col0 -> sigma; cols1..32 -> actA[0..31]
        {
            f16x8 a2 = ldA(actB, lane, 0);
#pragma unroll
            for (int n = 0; n < 3; n++) {
                float bv = bias[32 + 16 * n + cidx];
                f32x4 acc = {bv, bv, bv, bv};
                acc = MFMA16(a2, ldB(wB, 4096, n, lane), acc);
                int C = 16 * n + cidx;
                if (C == 0) {
#pragma unroll
                    for (int r = 0; r < 4; r++) sigw[g4 * 4 + r] = fmaxf(acc[r], 0.0f);
                } else if (C <= 32) {
                    stD(actA, C - 1, acc, true, g4);
                }
            }
        }
        // ---- L3: 32 -> 32, no act -> actB[0..31]
        {
            f16x8 a3 = ldA(actA, lane, 0);
#pragma unroll
            for (int n = 0; n < 2; n++) {
                float bv = bias[80 + 16 * n + cidx];
                f32x4 acc = {bv, bv, bv, bv};
                acc = MFMA16(a3, ldB(wB, 7168, n, lane), acc);
                stD(actB, 16 * n + cidx, acc, false, g4);
            }
        }
        // ---- L4: [h3|ed](64) -> 32, relu -> actA[0..31]
        {
            f16x8 a4a = ldA(actB, lane, 0);
            f16x8 a4b = ldA(actB, lane, 1);
#pragma unroll
            for (int n = 0; n < 2; n++) {
                float bv = bias[112 + 16 * n + cidx];
                f32x4 acc = {bv, bv, bv, bv};
                acc = MFMA16(a4a, ldB(wB, 9216, n * 2 + 0, lane), acc);
                acc = MFMA16(a4b, ldB(wB, 9216, n * 2 + 1, lane), acc);
                stD(actA, 16 * n + cidx, acc, true, g4);
            }
        }
        // ---- L5: 32 -> 3, sigmoid; + sigma out
        {
            f16x8 a5 = ldA(actA, lane, 0);
            float bv = bias[144 + cidx];
            f32x4 acc = {bv, bv, bv, bv};
            acc = MFMA16(a5, ldB(wB, 13312, 0, lane), acc);
            if (cidx < 3) {
#pragma unroll
                for (int r = 0; r < 4; r++) {
                    int p = g4 * 4 + r;
                    if (p < nv) out[(size_t)idxw[p] * 3 + cidx] = 1.0f / (1.0f + __expf(-acc[r]));
                }
            } else if (cidx == 3) {
#pragma unroll
                for (int r = 0; r < 4; r++) {
                    int p = g4 * 4 + r;
                    if (p < nv) out[(size_t)3 * P + idxw[p]] = sigw[p];
                }
            }
        }
    }
}

extern "C" void kernel_launch(void* const* d_in, const int* in_sizes, int n_in,
                              void* d_out, int out_size, void* d_ws, size_t ws_size,
                              hipStream_t stream) {
    const float* xs = (const float*)d_in[0];
    const float* dv = (const float*)d_in[1];
    const float* w1 = (const float*)d_in[2];
    const float* b1 = (const float*)d_in[3];
    const float* w2 = (const float*)d_in[4];
    const float* b2 = (const float*)d_in[5];
    const float* w3 = (const float*)d_in[6];
    const float* b3 = (const float*)d_in[7];
    const float* w4 = (const float*)d_in[8];
    const float* b4 = (const float*)d_in[9];
    const float* w5 = (const float*)d_in[10];
    const float* b5 = (const float*)d_in[11];
    float* out = (float*)d_out;
    int P = in_sizes[0] / 3;

    int* counts = (int*)d_ws;
    int* offsets = counts + 4096;
    int* cursor = offsets + 4104;
    int* sorted = cursor + 4096;

    hipMemsetAsync(counts, 0, 4096 * sizeof(int), stream);

    int blk = 256;
    int grd = (P + blk - 1) / blk;
    k_count<<<grd, blk, 0, stream>>>(xs, counts, out, P);
    k_scan<<<1, 64, 0, stream>>>(counts, offsets, cursor);
    k_scatter<<<grd, blk, 0, stream>>>(xs, cursor, sorted, P);
    k_mlp<<<NCELL, 256, 0, stream>>>(xs, dv, w1, b1, w2, b2, w3, b3, w4, b4, w5, b5,
                                     offsets, sorted, out, P);
}